// Round 7
// baseline (327.005 us; speedup 1.0000x reference)
//
#include <hip/hip_runtime.h>

#define BB 512
#define SS 1024
#define TT 48
#define CH 8           // chunks per sequence
#define CL 128         // steps per chunk

typedef __attribute__((ext_vector_type(8))) short short8;
typedef __attribute__((ext_vector_type(4))) float float4v;

// ---------- helpers ----------
__device__ __forceinline__ unsigned short f2bf(float x) {
    unsigned u = __float_as_uint(x);
    u += 0x7FFFu + ((u >> 16) & 1u);
    return (unsigned short)(u >> 16);
}
__device__ __forceinline__ unsigned pk2bf(float lo, float hi) {
#if __has_builtin(__builtin_amdgcn_cvt_pk_bf16_f32)
    typedef __bf16 bf16x2 __attribute__((ext_vector_type(2)));
    union { bf16x2 v; unsigned u; } cv;
    cv.v = __builtin_amdgcn_cvt_pk_bf16_f32(lo, hi);
    return cv.u;
#else
    return __builtin_amdgcn_perm(__float_as_uint(hi) + 0x8000u,
                                 __float_as_uint(lo) + 0x8000u, 0x07060302u);
#endif
}
__device__ __forceinline__ float wave_sum(float v) {
#pragma unroll
    for (int off = 32; off >= 1; off >>= 1) v += __shfl_xor(v, off, 64);
    return v;
}
__device__ __forceinline__ int wave_sum_i(int v) {
#pragma unroll
    for (int off = 32; off >= 1; off >>= 1) v += __shfl_xor(v, off, 64);
    return v;
}

// ---------- prep: lengths + gold-path numerator ----------
__global__ __launch_bounds__(256)
void crf_numer(const float* __restrict__ em, const int* __restrict__ tags,
               const int* __restrict__ mask, const float* __restrict__ start_tr,
               const float* __restrict__ end_tr, const float* __restrict__ trans,
               float* __restrict__ numer, int* __restrict__ lenArr) {
    const int b = blockIdx.x, tid = threadIdx.x;
    const float* emb = em + (size_t)b * SS * TT;
    const int* tg = tags + (size_t)b * SS;
    const int* mk = mask + (size_t)b * SS;
    int cnt = 0; float ns = 0.f;
    for (int s = tid; s < SS; s += 256) {
        int m = mk[s];
        cnt += (m != 0);
        if (s >= 1 && m) {
            int tp = tg[s - 1], tc = tg[s];
            ns += trans[tp * TT + tc] + emb[s * TT + tc];
        }
    }
    float wsum = wave_sum(ns);
    int wcnt = wave_sum_i(cnt);
    __shared__ float sf[4]; __shared__ int si[4];
    if ((tid & 63) == 0) { sf[tid >> 6] = wsum; si[tid >> 6] = wcnt; }
    __syncthreads();
    if (tid == 0) {
        float tot = sf[0] + sf[1] + sf[2] + sf[3];
        int L = si[0] + si[1] + si[2] + si[3];
        int t0 = tg[0];
        tot += start_tr[t0] + emb[t0] + end_tr[tg[L - 1]];
        numer[b] = tot;
        lenArr[b] = L;
    }
}

// ---------- Phase A: per-(batch,chunk) 48x48 product of M_t = diag(e_t)*expT ----------
// One wave per (b,c). C element (row = mt*16+q*4+r, col = nt*16+n) in C[mt][nt][r].
// Step: pack C -> B frags (verified kappa map, per column-tile), D = expT*C via
// 18 MFMAs (9 indep 2-deep chains), C = diag(e_t)*D (rows scaled). Steps t>=len
// skipped (wave-uniform) => matrix stays I for dead ranges.
__global__ __launch_bounds__(256, 1)
void crf_chunk(const float* __restrict__ em, const float* __restrict__ trans,
               const int* __restrict__ lenArr, float* __restrict__ Mout,
               float* __restrict__ scaleOut) {
    const int wid = blockIdx.x * 4 + (threadIdx.x >> 6);   // 0..4095
    const int lane = threadIdx.x & 63;
    const int b = wid >> 3, c = wid & 7;
    const int n = lane & 15, q = lane >> 4;

    const int len = lenArr[b];
    const int t0 = 1 + c * CL;
    int t1 = t0 + CL; if (t1 > len) t1 = len;   // steps t in [t0, t1)
    float* MO = Mout + (size_t)wid * (TT * TT);

    if (t1 <= t0) {   // wave-uniform: whole chunk beyond len -> identity
#pragma unroll
        for (int mt = 0; mt < 3; ++mt)
#pragma unroll
            for (int r = 0; r < 4; ++r) {
                int row = mt * 16 + q * 4 + r;
#pragma unroll
                for (int nt = 0; nt < 3; ++nt)
                    MO[row * TT + nt * 16 + n] = (row == nt * 16 + n) ? 1.0f : 0.0f;
            }
        if (lane == 0) scaleOut[wid] = 0.f;
        return;
    }

    // A-frags: A[m=s_out][k-slot(s_in)] = exp(trans[s_out][s_in])  (verified layout)
    short8 afr[3][2];
#pragma unroll
    for (int mt = 0; mt < 3; ++mt) {
        const int so = mt * 16 + n;
#pragma unroll
        for (int kt = 0; kt < 2; ++kt) {
            short8 a;
#pragma unroll
            for (int i = 0; i < 8; ++i) {
                int si_;
                if (kt == 0) si_ = (i < 4) ? (q * 4 + i) : (16 + q * 4 + (i - 4));
                else         si_ = (i < 4) ? (32 + q * 4 + i) : -1;
                a[i] = (si_ >= 0) ? (short)f2bf(__expf(trans[so * TT + si_])) : (short)0;
            }
            afr[mt][kt] = a;
        }
    }

    // C = I
    float C[3][3][4];
#pragma unroll
    for (int mt = 0; mt < 3; ++mt)
#pragma unroll
        for (int nt = 0; nt < 3; ++nt)
#pragma unroll
            for (int r = 0; r < 4; ++r)
                C[mt][nt][r] = (mt == nt && n == q * 4 + r) ? 1.0f : 0.0f;

    // bpermute byte-addresses for e broadcast: lane needs e[mt*16+q*4+r]
    int badr[12];
#pragma unroll
    for (int mt = 0; mt < 3; ++mt)
#pragma unroll
        for (int r = 0; r < 4; ++r)
            badr[mt * 4 + r] = 4 * (mt * 16 + q * 4 + r);

    const float* ep = em + (size_t)b * SS * TT + (lane & 47);  // lanes 48-63 dup 0-15
    float logscale = 0.f;
    const float4v Zv = {0.f, 0.f, 0.f, 0.f};

#define CSTEP(EV) {                                                                    \
    union { short8 v; unsigned w[4]; } B0[3], B1[3];                                   \
    _Pragma("unroll")                                                                  \
    for (int nt = 0; nt < 3; ++nt) {                                                   \
        B0[nt].w[0] = pk2bf(C[0][nt][0], C[0][nt][1]);                                 \
        B0[nt].w[1] = pk2bf(C[0][nt][2], C[0][nt][3]);                                 \
        B0[nt].w[2] = pk2bf(C[1][nt][0], C[1][nt][1]);                                 \
        B0[nt].w[3] = pk2bf(C[1][nt][2], C[1][nt][3]);                                 \
        B1[nt].w[0] = pk2bf(C[2][nt][0], C[2][nt][1]);                                 \
        B1[nt].w[1] = pk2bf(C[2][nt][2], C[2][nt][3]);                                 \
        B1[nt].w[2] = 0u; B1[nt].w[3] = 0u;                                            \
    }                                                                                  \
    float ee = __expf(EV);                                                             \
    float er[12];                                                                      \
    _Pragma("unroll")                                                                  \
    for (int i = 0; i < 12; ++i)                                                       \
        er[i] = __uint_as_float(__builtin_amdgcn_ds_bpermute(badr[i], __float_as_int(ee))); \
    _Pragma("unroll")                                                                  \
    for (int mt = 0; mt < 3; ++mt) {                                                   \
        _Pragma("unroll")                                                              \
        for (int nt = 0; nt < 3; ++nt) {                                               \
            float4v D = __builtin_amdgcn_mfma_f32_16x16x32_bf16(afr[mt][0], B0[nt].v, Zv, 0, 0, 0); \
            D = __builtin_amdgcn_mfma_f32_16x16x32_bf16(afr[mt][1], B1[nt].v, D, 0, 0, 0);          \
            C[mt][nt][0] = D[0] * er[mt * 4 + 0];                                      \
            C[mt][nt][1] = D[1] * er[mt * 4 + 1];                                      \
            C[mt][nt][2] = D[2] * er[mt * 4 + 2];                                      \
            C[mt][nt][3] = D[3] * er[mt * 4 + 3];                                      \
        }                                                                              \
    }                                                                                  \
}

#define CRENORM {                                                                      \
    float m_ = C[0][0][0];                                                             \
    _Pragma("unroll") for (int mt = 0; mt < 3; ++mt)                                   \
    _Pragma("unroll") for (int nt = 0; nt < 3; ++nt)                                   \
    _Pragma("unroll") for (int r = 0; r < 4; ++r) m_ = fmaxf(m_, C[mt][nt][r]);        \
    _Pragma("unroll") for (int off = 1; off < 64; off <<= 1)                           \
        m_ = fmaxf(m_, __shfl_xor(m_, off, 64));                                       \
    m_ = fmaxf(m_, 1e-30f);                                                            \
    logscale += __logf(m_);                                                            \
    float rm_ = 1.0f / m_;                                                             \
    _Pragma("unroll") for (int mt = 0; mt < 3; ++mt)                                   \
    _Pragma("unroll") for (int nt = 0; nt < 3; ++nt)                                   \
    _Pragma("unroll") for (int r = 0; r < 4; ++r) C[mt][nt][r] *= rm_;                 \
}

    float ea[8], eb[8];
#pragma unroll
    for (int k = 0; k < 8; ++k) {
        int tt = t0 + k; tt = tt < t1 ? tt : t1 - 1;
        ea[k] = ep[(size_t)tt * TT];
    }
    int t = t0;
    for (; t + 16 <= t1; t += 16) {
#pragma unroll
        for (int k = 0; k < 8; ++k) eb[k] = ep[(size_t)(t + 8 + k) * TT];
        CSTEP(ea[0]) CSTEP(ea[1]) CSTEP(ea[2]) CSTEP(ea[3])
        CSTEP(ea[4]) CSTEP(ea[5]) CSTEP(ea[6]) CSTEP(ea[7])
        CRENORM
#pragma unroll
        for (int k = 0; k < 8; ++k) {
            int tt = t + 16 + k; tt = tt < t1 ? tt : t1 - 1;
            ea[k] = ep[(size_t)tt * TT];
        }
        CSTEP(eb[0]) CSTEP(eb[1]) CSTEP(eb[2]) CSTEP(eb[3])
        CSTEP(eb[4]) CSTEP(eb[5]) CSTEP(eb[6]) CSTEP(eb[7])
        CRENORM
    }
    int rem = t1 - t;                     // 0..15; rows t..t+7 already in ea
#pragma unroll
    for (int k = 0; k < 8; ++k) { if (k < rem) CSTEP(ea[k]) }
    CRENORM
    if (rem > 8) {
#pragma unroll
        for (int k = 0; k < 8; ++k) {
            int tt = t + 8 + k; tt = tt < t1 ? tt : t1 - 1;
            eb[k] = ep[(size_t)tt * TT];
        }
#pragma unroll
        for (int k = 0; k < 8; ++k) { if (k + 8 < rem) CSTEP(eb[k]) }
        CRENORM
    }

    // store f32 matrix row-major + scale
#pragma unroll
    for (int mt = 0; mt < 3; ++mt)
#pragma unroll
        for (int r = 0; r < 4; ++r) {
            int row = mt * 16 + q * 4 + r;
#pragma unroll
            for (int nt = 0; nt < 3; ++nt)
                MO[row * TT + nt * 16 + n] = C[mt][nt][r];
        }
    if (lane == 0) scaleOut[wid] = logscale;
#undef CSTEP
#undef CRENORM
}

// ---------- Phase B: combine — p0 through 8 chunk matrices, then log ----------
__global__ __launch_bounds__(64)
void crf_comb(const float* __restrict__ em, const float* __restrict__ start_tr,
              const float* __restrict__ end_tr, const float* __restrict__ Mall,
              const float* __restrict__ scaleAll, float* __restrict__ denomArr) {
    const int b = blockIdx.x, lane = threadIdx.x;
    __shared__ float pl[TT];
    float p = 0.f;
    if (lane < TT) p = __expf(start_tr[lane] + em[(size_t)b * SS * TT + lane]);
    float logscale = 0.f;
#pragma unroll 1
    for (int c = 0; c < CH; ++c) {
        if (lane < TT) pl[lane] = p;
        __syncthreads();
        const float* M = Mall + ((size_t)(b * CH + c)) * (TT * TT) + lane * TT;
        float acc = 0.f;
        if (lane < TT) {
#pragma unroll
            for (int j = 0; j < TT; j += 4) {
                float4 m4 = *(const float4*)(M + j);
                acc = fmaf(m4.x, pl[j], acc);
                acc = fmaf(m4.y, pl[j + 1], acc);
                acc = fmaf(m4.z, pl[j + 2], acc);
                acc = fmaf(m4.w, pl[j + 3], acc);
            }
        }
        logscale += scaleAll[b * CH + c];
        float mm = acc;
#pragma unroll
        for (int off = 1; off < 64; off <<= 1) mm = fmaxf(mm, __shfl_xor(mm, off, 64));
        mm = fmaxf(mm, 1e-30f);
        logscale += __logf(mm);
        p = acc * (1.0f / mm);
        __syncthreads();
    }
    float pe = (lane < TT) ? p * __expf(end_tr[lane]) : 0.f;
    pe = wave_sum(pe);
    if (lane == 0) denomArr[b] = logscale + __logf(pe);
}

__global__ __launch_bounds__(64)
void crf_reduce(const float* __restrict__ denom, const float* __restrict__ numer,
                float* __restrict__ out) {
    int lane = threadIdx.x;
    float s = 0.f;
    for (int i = lane; i < BB; i += 64) s += denom[i] - numer[i];
    s = wave_sum(s);
    if (lane == 0) out[0] = s * (1.0f / (float)BB);
}

extern "C" void kernel_launch(void* const* d_in, const int* in_sizes, int n_in,
                              void* d_out, int out_size, void* d_ws, size_t ws_size,
                              hipStream_t stream) {
    const float* emissions = (const float*)d_in[0];
    const int*   tags      = (const int*)d_in[1];
    const int*   mask      = (const int*)d_in[2];
    const float* start_tr  = (const float*)d_in[3];
    const float* end_tr    = (const float*)d_in[4];
    const float* trans     = (const float*)d_in[5];

    char* ws = (char*)d_ws;
    const size_t MF_BYTES = (size_t)BB * CH * TT * TT * 4;   // 37,748,736
    float* MF     = (float*)ws;
    float* scaleA = (float*)(ws + MF_BYTES);                 // 4096 f32
    float* denom  = (float*)(ws + MF_BYTES + 16384);         // 512 f32
    float* numer  = (float*)(ws + MF_BYTES + 18432);         // 512 f32
    int*   lenA   = (int*)(ws + MF_BYTES + 20480);           // 512 i32
    // total ~37.77 MB; proven available (rounds 2-4 used 50.3 MB)

    crf_numer<<<BB, 256, 0, stream>>>(emissions, tags, mask, start_tr, end_tr,
                                      trans, numer, lenA);
    crf_chunk<<<BB * CH / 4, 256, 0, stream>>>(emissions, trans, lenA, MF, scaleA);
    crf_comb<<<BB, 64, 0, stream>>>(emissions, start_tr, end_tr, MF, scaleA, denom);
    crf_reduce<<<1, 64, 0, stream>>>(denom, numer, (float*)d_out);
}